// Round 1
// baseline (1244.379 us; speedup 1.0000x reference)
//
#include <hip/hip_runtime.h>
#include <math.h>

// ---------------- problem constants ----------------
#define D        256
#define NINNER   2048
#define NROW     2049          // 2048 + dustbin
#define SP       2064          // padded row stride (floats), 16B-aligned rows
#define ITERS_N  100
#define EPS_F    0.8f
#define TAU_F    1.02f
#define NB       256           // persistent blocks
#define NT       256           // threads per block

// ws layout (in floats)
#define SZ_MAT   (2049u * 2064u)          // 4229136
#define OFF_E    0u
#define OFF_F    SZ_MAT
#define OFF_WU   (2u * SZ_MAT)            // float[2049] exp(u), padded to 2064
#define OFF_WV   (OFF_WU + 2064u)         // float[2049] exp(v)
#define OFF_CU   (OFF_WV + 2064u)         // unsigned[8*64]: u-phase counters, 8 lines
#define OFF_CV   (OFF_CU + 512u)          // unsigned[8*64]: v-phase counters
#define OFF_MAX0 (OFF_CV + 512u)
#define OFF_IDX0 (OFF_MAX0 + 2048u)
#define OFF_IDX1 (OFF_IDX0 + 2048u)
#define OFF_MS0  (OFF_IDX1 + 2048u)
#define OFF_VLD0 (OFF_MS0 + 2048u)

// d_out layout (floats)
#define OOFF_I0  (2049u * 2049u)          // 4198401
#define OOFF_I1  (OOFF_I0 + 2048u)
#define OOFF_S0  (OOFF_I1 + 2048u)
#define OOFF_S1  (OOFF_S0 + 2048u)

// ---------------- K1: fp32 GEMM -> E = exp(scores), F = E^T (fused) ----------------
__global__ __launch_bounds__(256) void k_gemm(const float* __restrict__ A,
                                              const float* __restrict__ Bm,
                                              float* __restrict__ E,
                                              float* __restrict__ F) {
    __shared__ float As[8][64];
    __shared__ float Bs[8][64];
    const int tid = threadIdx.x;
    const int tx = tid & 15, ty = tid >> 4;
    const int row0 = blockIdx.y * 64, col0 = blockIdx.x * 64;
    float acc[4][4] = {};
    const int lr = tid >> 6, lc = tid & 63;
    for (int k0 = 0; k0 < D; k0 += 8) {
        As[lr][lc]     = A[(k0 + lr) * NINNER + row0 + lc];
        As[lr + 4][lc] = A[(k0 + lr + 4) * NINNER + row0 + lc];
        Bs[lr][lc]     = Bm[(k0 + lr) * NINNER + col0 + lc];
        Bs[lr + 4][lc] = Bm[(k0 + lr + 4) * NINNER + col0 + lc];
        __syncthreads();
#pragma unroll
        for (int kk = 0; kk < 8; ++kk) {
            const float4 av = *(const float4*)&As[kk][ty * 4];
            const float4 bv = *(const float4*)&Bs[kk][tx * 4];
            const float a_[4] = {av.x, av.y, av.z, av.w};
            const float b_[4] = {bv.x, bv.y, bv.z, bv.w};
#pragma unroll
            for (int r = 0; r < 4; ++r)
#pragma unroll
                for (int c = 0; c < 4; ++c)
                    acc[r][c] = fmaf(a_[r], b_[c], acc[r][c]);
        }
        __syncthreads();
    }
    float o[4][4];
#pragma unroll
    for (int r = 0; r < 4; ++r)
#pragma unroll
        for (int c = 0; c < 4; ++c)
            o[r][c] = expf(acc[r][c] * 0.0625f);
    const int row = row0 + ty * 4, col = col0 + tx * 4;
#pragma unroll
    for (int r = 0; r < 4; ++r)     // E tile
        *(float4*)(E + (size_t)(row + r) * SP + col)
            = make_float4(o[r][0], o[r][1], o[r][2], o[r][3]);
#pragma unroll
    for (int c = 0; c < 4; ++c)     // F tile (transposed)
        *(float4*)(F + (size_t)(col + c) * SP + row)
            = make_float4(o[0][c], o[1][c], o[2][c], o[3][c]);
}

// ---------------- K2: bins for E and F + wv/counter init ----------------
__global__ __launch_bounds__(256) void k_init(float* __restrict__ E,
                                              float* __restrict__ F,
                                              float* __restrict__ wv,
                                              unsigned* __restrict__ cu,
                                              unsigned* __restrict__ cv,
                                              const float* __restrict__ alpha) {
    const int t = blockIdx.x * 256 + threadIdx.x;
    const float ea = expf(alpha[0]);
    if (t < NINNER) {
        E[(size_t)t * SP + NINNER] = ea;        // E bin column (epilogue only)
        F[(size_t)t * SP + NINNER] = ea;        // F bin column
        wv[t] = 1.0f;                           // v0 = 0 -> exp(v0) = 1
    }
    if (t <= NINNER) {
        E[(size_t)NINNER * SP + t] = ea;        // E bin row (+corner)
        F[(size_t)NINNER * SP + t] = ea;        // F bin row (+corner)
    }
    if (t < 8) {
        cu[t * 64] = 0u;                        // no u-phase done yet
        cv[t * 64] = NB / 8;                    // v^0 "published" => sum == NB
    }
}

// ---------------- K3: persistent Sinkhorn — counter-gated single-buffer dataflow ----
// Block b owns rows [8b,8b+8) of E and cols [8b,8b+8) of F in registers.
// Per phase: ONE thread per block polls 8 split counter lines (256 scalar
// pollers chip-wide — kills the L3 poll storm of the old per-slot tag
// scheme), then the whole block does guaranteed-hit 4B value loads.
// Producer wave: tid<8 store exp(u) (agent-relaxed, straight to L3), then
// tid==0 of the SAME wave fetch_add(+1, release) — release drains vmcnt,
// so values are at the coherence point before the increment is visible.
// Single-buffering is safe: counter spread across blocks is provably <= 1
// phase, so phase-t values are fully consumed before any t+1 overwrite.
// Dustbin potentials are locally replicated (bit-identical in every block).
__global__ __launch_bounds__(256, 1) void k_sinkhorn(const float* __restrict__ E,
                                                     const float* __restrict__ F,
                                                     float* __restrict__ wu,
                                                     float* __restrict__ wv,
                                                     unsigned* __restrict__ cu,
                                                     unsigned* __restrict__ cv,
                                                     const float* __restrict__ alpha) {
    const int b = blockIdx.x, tid = threadIdx.x;
    const int lane = tid & 63, wid = tid >> 6;
    const int base = b * 8;
    __shared__ float red[2][4][9];

    const float norm = -8.317766166719343f;            // -log(4096)
    const float logbin = 7.624618986159398f + norm;     // log(2048) + norm
    const float ea = expf(alpha[0]);

    float eR[8][8], fR[8][8];
#pragma unroll
    for (int r = 0; r < 8; ++r) {
        const float* rowE = E + (size_t)(base + r) * SP;
        const float* rowF = F + (size_t)(base + r) * SP;
#pragma unroll
        for (int q = 0; q < 8; ++q) {
            eR[r][q] = rowE[q * 256 + tid];
            fR[r][q] = rowF[q * 256 + tid];
        }
    }

    float u = 0.0f, v = 0.0f;              // potentials for row/col base+tid (tid<8)
    float ub = 0.0f, vb = 0.0f;            // dustbin potentials — local replicas
    float eub = 1.0f, evb = 1.0f;          // exp(ub), exp(vb)

    for (int it = 0; it < ITERS_N; ++it) {
        const unsigned tgt = (unsigned)(NB * (it + 1));
        // ---- phase A: wait v-phase it complete, produce u^{it+1} ----
        {
            if (tid == 0) {
                for (;;) {
                    unsigned s = 0;
#pragma unroll
                    for (int k = 0; k < 8; ++k)
                        s += __hip_atomic_load(cv + k * 64, __ATOMIC_RELAXED,
                                               __HIP_MEMORY_SCOPE_AGENT);
                    if (s >= tgt) break;
                    __builtin_amdgcn_s_sleep(1);
                }
            }
            __syncthreads();
            float w[8];
#pragma unroll
            for (int q = 0; q < 8; ++q)
                w[q] = __hip_atomic_load(wv + q * 256 + tid, __ATOMIC_RELAXED,
                                         __HIP_MEMORY_SCOPE_AGENT);
            float p[8];
#pragma unroll
            for (int r = 0; r < 8; ++r) {
                float s = 0.0f;
#pragma unroll
                for (int q = 0; q < 8; ++q) s = fmaf(eR[r][q], w[q], s);
                p[r] = s;
            }
            float t = w[0] + w[1] + w[2] + w[3] + w[4] + w[5] + w[6] + w[7];
#pragma unroll
            for (int r = 0; r < 8; ++r) {
                float s = p[r];
#pragma unroll
                for (int m = 1; m < 64; m <<= 1) s += __shfl_xor(s, m, 64);
                if (lane == 0) red[0][wid][r] = s;
            }
#pragma unroll
            for (int m = 1; m < 64; m <<= 1) t += __shfl_xor(t, m, 64);
            if (lane == 0) red[0][wid][8] = t;
            __syncthreads();
            // local dustbin update (every thread, identical result)
            const float tsum = red[0][0][8] + red[0][1][8] + red[0][2][8] + red[0][3][8];
            const float Sbin = ea * (tsum + evb);
            ub = ub + EPS_F * ((logbin - logf(Sbin)) / TAU_F - ub);
            if (tid < 8) {
                const float S = red[0][0][tid] + red[0][1][tid] + red[0][2][tid] + red[0][3][tid]
                              + ea * evb;
                const float unew = (norm - logf(S)) / TAU_F;
                u = u + EPS_F * (unew - u);
                __hip_atomic_store(wu + base + tid, expf(u),
                                   __ATOMIC_RELAXED, __HIP_MEMORY_SCOPE_AGENT);
            }
            if (tid == 0)   // same wave as the stores: release drains vmcnt first
                __hip_atomic_fetch_add(cu + (b & 7) * 64, 1u,
                                       __ATOMIC_RELEASE, __HIP_MEMORY_SCOPE_AGENT);
            eub = expf(ub);
        }
        // ---- phase B: wait u-phase it+1 complete, produce v^{it+1} ----
        {
            if (tid == 0) {
                for (;;) {
                    unsigned s = 0;
#pragma unroll
                    for (int k = 0; k < 8; ++k)
                        s += __hip_atomic_load(cu + k * 64, __ATOMIC_RELAXED,
                                               __HIP_MEMORY_SCOPE_AGENT);
                    if (s >= tgt) break;
                    __builtin_amdgcn_s_sleep(1);
                }
            }
            __syncthreads();
            float w[8];
#pragma unroll
            for (int q = 0; q < 8; ++q)
                w[q] = __hip_atomic_load(wu + q * 256 + tid, __ATOMIC_RELAXED,
                                         __HIP_MEMORY_SCOPE_AGENT);
            float p[8];
#pragma unroll
            for (int r = 0; r < 8; ++r) {
                float s = 0.0f;
#pragma unroll
                for (int q = 0; q < 8; ++q) s = fmaf(fR[r][q], w[q], s);
                p[r] = s;
            }
            float t = w[0] + w[1] + w[2] + w[3] + w[4] + w[5] + w[6] + w[7];
#pragma unroll
            for (int r = 0; r < 8; ++r) {
                float s = p[r];
#pragma unroll
                for (int m = 1; m < 64; m <<= 1) s += __shfl_xor(s, m, 64);
                if (lane == 0) red[1][wid][r] = s;
            }
#pragma unroll
            for (int m = 1; m < 64; m <<= 1) t += __shfl_xor(t, m, 64);
            if (lane == 0) red[1][wid][8] = t;
            __syncthreads();
            const float tsum = red[1][0][8] + red[1][1][8] + red[1][2][8] + red[1][3][8];
            const float Tbin = ea * (tsum + eub);
            vb = vb + EPS_F * ((logbin - logf(Tbin)) / TAU_F - vb);
            if (tid < 8) {
                const float T = red[1][0][tid] + red[1][1][tid] + red[1][2][tid] + red[1][3][tid]
                              + ea * eub;
                const float vnew = (norm - logf(T)) / TAU_F;
                v = v + EPS_F * (vnew - v);
                __hip_atomic_store(wv + base + tid, expf(v),
                                   __ATOMIC_RELAXED, __HIP_MEMORY_SCOPE_AGENT);
            }
            if (tid == 0)
                __hip_atomic_fetch_add(cv + (b & 7) * 64, 1u,
                                       __ATOMIC_RELEASE, __HIP_MEMORY_SCOPE_AGENT);
            evb = expf(vb);
        }
    }
    // publish final dustbin scalings once for the epilogue (kernel-end flush
    // makes these visible to k_finish)
    if (b == NB - 1 && tid == 0) {
        wu[NINNER] = eub;
        wv[NINNER] = evb;
    }
}

// ---------------- K4: fused epilogue — out0 = exp(Z), row argmax, col argmax ----------
__global__ __launch_bounds__(256) void k_finish(const float* __restrict__ E,
                                                const float* __restrict__ F,
                                                const float* __restrict__ wu,
                                                const float* __restrict__ wv,
                                                float* __restrict__ out,
                                                float* __restrict__ max0,
                                                int* __restrict__ idx0,
                                                int* __restrict__ idx1) {
    const int i = blockIdx.x;                 // 0..2048
    const int tid = threadIdx.x;
    const int lane = tid & 63, wid = tid >> 6;
    __shared__ float sb[4]; __shared__ int si[4];

    // --- row part: write out row i, argmax over inner cols ---
    {
        const float wui = wu[i] * 4096.0f;     // * exp(-norm)
        const float* row = E + (size_t)i * SP;
        float best = -1.0f; int bidx = 0;
        for (int j = tid; j < NROW; j += 256) {
            const float val = row[j] * wv[j] * wui;
            out[(size_t)i * NROW + j] = val;
            if (j < NINNER && val > best) { best = val; bidx = j; }
        }
        if (i < NINNER) {
#pragma unroll
            for (int m = 1; m < 64; m <<= 1) {
                const float ob = __shfl_xor(best, m, 64);
                const int   oi = __shfl_xor(bidx, m, 64);
                if (ob > best || (ob == best && oi < bidx)) { best = ob; bidx = oi; }
            }
            if (lane == 0) { sb[wid] = best; si[wid] = bidx; }
            __syncthreads();
            if (tid == 0) {
                for (int k = 1; k < 4; ++k)
                    if (sb[k] > best || (sb[k] == best && si[k] < bidx)) { best = sb[k]; bidx = si[k]; }
                max0[i] = best; idx0[i] = bidx;
            }
        }
    }

    // --- col part: argmax of column i over inner rows (via F) ---
    if (i < NINNER) {
        __syncthreads();                          // sb/si reuse safety
        const float* row = F + (size_t)i * SP;
        float best = -1.0f; int bidx = 0;
        for (int r = tid; r < NINNER; r += 256) {
            const float q = row[r] * wu[r];
            if (q > best) { best = q; bidx = r; }
        }
#pragma unroll
        for (int m = 1; m < 64; m <<= 1) {
            const float ob = __shfl_xor(best, m, 64);
            const int   oi = __shfl_xor(bidx, m, 64);
            if (ob > best || (ob == best && oi < bidx)) { best = ob; bidx = oi; }
        }
        if (lane == 0) { sb[wid] = best; si[wid] = bidx; }
        __syncthreads();
        if (tid == 0) {
            for (int k = 1; k < 4; ++k)
                if (sb[k] > best || (sb[k] == best && si[k] < bidx)) { best = sb[k]; bidx = si[k]; }
            idx1[i] = bidx;
        }
    }
}

// ---------------- K5a/K5b: mutual matching ----------------
__global__ __launch_bounds__(256) void k_match0(const float* __restrict__ max0,
                                                const int* __restrict__ idx0,
                                                const int* __restrict__ idx1,
                                                float* __restrict__ ms0,
                                                int* __restrict__ vld0,
                                                float* __restrict__ out) {
    const int i = blockIdx.x * 256 + threadIdx.x;
    if (i >= NINNER) return;
    const int j = idx0[i];
    const bool mut = (idx1[j] == i);
    const float ms = mut ? max0[i] : 0.0f;
    const bool val = mut && (ms > 0.2f);
    ms0[i] = ms; vld0[i] = val ? 1 : 0;
    out[OOFF_I0 + i] = val ? (float)j : -1.0f;
    out[OOFF_S0 + i] = ms;
}
__global__ __launch_bounds__(256) void k_match1(const int* __restrict__ idx0,
                                                const int* __restrict__ idx1,
                                                const float* __restrict__ ms0,
                                                const int* __restrict__ vld0,
                                                float* __restrict__ out) {
    const int j = blockIdx.x * 256 + threadIdx.x;
    if (j >= NINNER) return;
    const int i = idx1[j];
    const bool mut = (idx0[i] == j);
    const float ms = mut ? ms0[i] : 0.0f;
    const bool val = mut && (vld0[i] != 0);
    out[OOFF_I1 + j] = val ? (float)i : -1.0f;
    out[OOFF_S1 + j] = ms;
}

// ---------------- host ----------------
extern "C" void kernel_launch(void* const* d_in, const int* in_sizes, int n_in,
                              void* d_out, int out_size, void* d_ws, size_t ws_size,
                              hipStream_t stream) {
    const float* A     = (const float*)d_in[0];   // mdesc0 (1,256,2048)
    const float* Bm    = (const float*)d_in[1];   // mdesc1 (1,256,2048)
    const float* alpha = (const float*)d_in[2];   // bin_score scalar

    float* ws = (float*)d_ws;
    float* E      = ws + OFF_E;
    float* F      = ws + OFF_F;
    float* wu     = ws + OFF_WU;
    float* wv     = ws + OFF_WV;
    unsigned* cu  = (unsigned*)(ws + OFF_CU);
    unsigned* cv  = (unsigned*)(ws + OFF_CV);
    float* max0   = ws + OFF_MAX0;
    int*   idx0   = (int*)(ws + OFF_IDX0);
    int*   idx1   = (int*)(ws + OFF_IDX1);
    float* ms0    = ws + OFF_MS0;
    int*   vld0   = (int*)(ws + OFF_VLD0);
    float* out    = (float*)d_out;

    k_gemm<<<dim3(32, 32), 256, 0, stream>>>(A, Bm, E, F);
    k_init<<<dim3(16), 256, 0, stream>>>(E, F, wv, cu, cv, alpha);
    k_sinkhorn<<<dim3(NB), NT, 0, stream>>>(E, F, wu, wv, cu, cv, alpha);
    k_finish<<<dim3(NROW), 256, 0, stream>>>(E, F, wu, wv, out, max0, idx0, idx1);
    k_match0<<<dim3(8), 256, 0, stream>>>(max0, idx0, idx1, ms0, vld0, out);
    k_match1<<<dim3(8), 256, 0, stream>>>(idx0, idx1, ms0, vld0, out);
}

// Round 2
// 1140.050 us; speedup vs baseline: 1.0915x; 1.0915x over previous
//
#include <hip/hip_runtime.h>
#include <math.h>

// ---------------- problem constants ----------------
#define D        256
#define NINNER   2048
#define NROW     2049          // 2048 + dustbin
#define SP       2064          // padded row stride (floats), 16B-aligned rows
#define ITERS_N  100
#define EPS_F    0.8f
#define TAU_F    1.02f
#define NB_S     128           // persistent sinkhorn blocks
#define NT_S     512           // threads per sinkhorn block
#define ROWS     16            // rows (cols) owned per block

typedef unsigned long long u64;
typedef __attribute__((ext_vector_type(4))) unsigned int uint4v;

// pair buffers: u64 slots, (tag<<32)|float_bits, double-buffered by tag parity
#define PSTRIDE  2112u         // pairs per buffer (2048 iter slots + slot 2048 final-only)

// ws layout (in floats)
#define SZ_MAT   (2049u * 2064u)          // 4229136
#define OFF_E    0u
#define OFF_F    SZ_MAT
#define OFF_WUP  (2u * SZ_MAT)                  // u64[2][PSTRIDE] = 4*PSTRIDE floats
#define OFF_WVP  (OFF_WUP + 4u * PSTRIDE)
#define OFF_MAX0 (OFF_WVP + 4u * PSTRIDE)
#define OFF_IDX0 (OFF_MAX0 + 2048u)
#define OFF_IDX1 (OFF_IDX0 + 2048u)
#define OFF_MS0  (OFF_IDX1 + 2048u)
#define OFF_VLD0 (OFF_MS0 + 2048u)

// d_out layout (floats)
#define OOFF_I0  (2049u * 2049u)          // 4198401
#define OOFF_I1  (OOFF_I0 + 2048u)
#define OOFF_S0  (OOFF_I1 + 2048u)
#define OOFF_S1  (OOFF_S0 + 2048u)

__device__ __forceinline__ float    pair_val(u64 x) { return __uint_as_float((unsigned)x); }
__device__ __forceinline__ unsigned pair_tag(u64 x) { return (unsigned)(x >> 32); }
__device__ __forceinline__ u64 make_pair(float v, unsigned t) {
    return ((u64)t << 32) | (u64)__float_as_uint(v);
}

// ---------------- K1: fp32 GEMM -> E = exp(scores), F = E^T (fused) ----------------
__global__ __launch_bounds__(256) void k_gemm(const float* __restrict__ A,
                                              const float* __restrict__ Bm,
                                              float* __restrict__ E,
                                              float* __restrict__ F) {
    __shared__ float As[8][64];
    __shared__ float Bs[8][64];
    const int tid = threadIdx.x;
    const int tx = tid & 15, ty = tid >> 4;
    const int row0 = blockIdx.y * 64, col0 = blockIdx.x * 64;
    float acc[4][4] = {};
    const int lr = tid >> 6, lc = tid & 63;
    for (int k0 = 0; k0 < D; k0 += 8) {
        As[lr][lc]     = A[(k0 + lr) * NINNER + row0 + lc];
        As[lr + 4][lc] = A[(k0 + lr + 4) * NINNER + row0 + lc];
        Bs[lr][lc]     = Bm[(k0 + lr) * NINNER + col0 + lc];
        Bs[lr + 4][lc] = Bm[(k0 + lr + 4) * NINNER + col0 + lc];
        __syncthreads();
#pragma unroll
        for (int kk = 0; kk < 8; ++kk) {
            const float4 av = *(const float4*)&As[kk][ty * 4];
            const float4 bv = *(const float4*)&Bs[kk][tx * 4];
            const float a_[4] = {av.x, av.y, av.z, av.w};
            const float b_[4] = {bv.x, bv.y, bv.z, bv.w};
#pragma unroll
            for (int r = 0; r < 4; ++r)
#pragma unroll
                for (int c = 0; c < 4; ++c)
                    acc[r][c] = fmaf(a_[r], b_[c], acc[r][c]);
        }
        __syncthreads();
    }
    float o[4][4];
#pragma unroll
    for (int r = 0; r < 4; ++r)
#pragma unroll
        for (int c = 0; c < 4; ++c)
            o[r][c] = expf(acc[r][c] * 0.0625f);
    const int row = row0 + ty * 4, col = col0 + tx * 4;
#pragma unroll
    for (int r = 0; r < 4; ++r)     // E tile
        *(float4*)(E + (size_t)(row + r) * SP + col)
            = make_float4(o[r][0], o[r][1], o[r][2], o[r][3]);
#pragma unroll
    for (int c = 0; c < 4; ++c)     // F tile (transposed)
        *(float4*)(F + (size_t)(col + c) * SP + row)
            = make_float4(o[0][c], o[1][c], o[2][c], o[3][c]);
}

// ---------------- K2: bins for E and F + wv pair init (tag 0) ----------------
__global__ __launch_bounds__(256) void k_init(float* __restrict__ E,
                                              float* __restrict__ F,
                                              u64* __restrict__ wvb0,
                                              const float* __restrict__ alpha) {
    const int t = blockIdx.x * 256 + threadIdx.x;
    const float ea = expf(alpha[0]);
    if (t < NINNER) {
        E[(size_t)t * SP + NINNER] = ea;        // E bin column (for epilogue only)
        F[(size_t)t * SP + NINNER] = ea;        // F bin column
        wvb0[t] = make_pair(1.0f, 0u);          // v0 = 0 -> wv = 1, tag 0
    }
    if (t <= NINNER) {
        E[(size_t)NINNER * SP + t] = ea;        // E bin row (+corner)
        F[(size_t)NINNER * SP + t] = ea;        // F bin row (+corner)
    }
}

// ---------------- fused tag+value poll: 4 contiguous slots, 2 wide loads ----------
// Detection IS delivery: the 16B sc0/sc1 loads carry both tags and values,
// so a phase costs one L3 round trip after the producer's store lands.
// Contiguous 32B per thread => 2 requests/round (v0: 8 strided 8B requests).
__device__ __forceinline__ void poll4(const u64* buf, int tid, unsigned want, float* w) {
    const u64* p = buf + 4 * (size_t)tid;
    uint4v x, y;
    for (;;) {
        asm volatile("global_load_dwordx4 %0, %2, off sc0 sc1\n\t"
                     "global_load_dwordx4 %1, %2, off offset:16 sc0 sc1\n\t"
                     "s_waitcnt vmcnt(0)"
                     : "=&v"(x), "=&v"(y)
                     : "v"(p)
                     : "memory");
        if (x.y == want && x.w == want && y.y == want && y.w == want) break;
        __builtin_amdgcn_s_sleep(1);     // ~64 cyc backoff
    }
    __builtin_amdgcn_sched_barrier(0);   // rule-18 insurance: no hoisting past the waitcnt
    w[0] = __uint_as_float(x.x); w[1] = __uint_as_float(x.z);
    w[2] = __uint_as_float(y.x); w[3] = __uint_as_float(y.z);
}

// ---------------- K3: persistent Sinkhorn — barrier-free tagged dataflow ----------
// 128 blocks x 512 threads. Block b owns rows [16b,16b+16) of E and cols of F
// in registers (eR/fR[16][4], one float4 per row: thread t covers j=4t..4t+3).
// wu/wv (inner 2048) exchanged as (tag,value) 8B atoms, double-buffered by tag
// parity — identical protocol to the proven v0 (skew bound < 2 iters per
// parity buffer; 0xAA poison never matches wanted tags 0..100). Dustbin
// potentials locally replicated (bit-identical in every block).
__global__ __launch_bounds__(512, 2) void k_sinkhorn(const float* __restrict__ E,
                                                     const float* __restrict__ F,
                                                     u64* wub, u64* wvb,
                                                     const float* __restrict__ alpha) {
    const int b = blockIdx.x, tid = threadIdx.x;
    const int lane = tid & 63, wid = tid >> 6;
    const int base = b * ROWS;
    const bool lastb = (b == NB_S - 1);
    __shared__ float red[2][8][17];

    const float norm = -8.317766166719343f;            // -log(4096)
    const float logbin = 7.624618986159398f + norm;     // log(2048) + norm
    const float ea = expf(alpha[0]);

    float eR[ROWS][4], fR[ROWS][4];
#pragma unroll
    for (int r = 0; r < ROWS; ++r) {
        const float4 ev = *(const float4*)(E + (size_t)(base + r) * SP + 4 * tid);
        const float4 fv = *(const float4*)(F + (size_t)(base + r) * SP + 4 * tid);
        eR[r][0] = ev.x; eR[r][1] = ev.y; eR[r][2] = ev.z; eR[r][3] = ev.w;
        fR[r][0] = fv.x; fR[r][1] = fv.y; fR[r][2] = fv.z; fR[r][3] = fv.w;
    }

    float u = 0.0f, v = 0.0f;              // potentials for row/col base+tid (tid<16)
    float ub = 0.0f, vb = 0.0f;            // dustbin potentials — local replicas
    float eub = 1.0f, evb = 1.0f;          // exp(ub), exp(vb)

    for (int it = 0; it < ITERS_N; ++it) {
        // ---- phase A: consume wv tag it, produce wu tag it+1 ----
        {
            const u64* src = wvb + (size_t)(it & 1) * PSTRIDE;
            u64* dst = wub + (size_t)((it + 1) & 1) * PSTRIDE;
            const unsigned prod = (unsigned)(it + 1);
            float w[4];
            poll4(src, tid, (unsigned)it, w);
            float p[ROWS];
#pragma unroll
            for (int r = 0; r < ROWS; ++r) {
                float s = 0.0f;
#pragma unroll
                for (int q = 0; q < 4; ++q) s = fmaf(eR[r][q], w[q], s);
                p[r] = s;
            }
            float t = w[0] + w[1] + w[2] + w[3];
#pragma unroll
            for (int r = 0; r < ROWS; ++r) {
                float s = p[r];
#pragma unroll
                for (int m = 1; m < 64; m <<= 1) s += __shfl_xor(s, m, 64);
                if (lane == 0) red[0][wid][r] = s;
            }
#pragma unroll
            for (int m = 1; m < 64; m <<= 1) t += __shfl_xor(t, m, 64);
            if (lane == 0) red[0][wid][16] = t;
            __syncthreads();
            // local dustbin update (every thread, identical result)
            float tsum = 0.0f;
#pragma unroll
            for (int k = 0; k < 8; ++k) tsum += red[0][k][16];
            const float Sbin = ea * (tsum + evb);
            ub = ub + EPS_F * ((logbin - logf(Sbin)) / TAU_F - ub);
            if (tid < ROWS) {
                float S = ea * evb;
#pragma unroll
                for (int k = 0; k < 8; ++k) S += red[0][k][tid];
                const float unew = (norm - logf(S)) / TAU_F;
                u = u + EPS_F * (unew - u);
                __hip_atomic_store(dst + base + tid, make_pair(expf(u), prod),
                                   __ATOMIC_RELAXED, __HIP_MEMORY_SCOPE_AGENT);
            }
            eub = expf(ub);
        }
        // ---- phase B: consume wu tag it+1, produce wv tag it+1 ----
        {
            const u64* src = wub + (size_t)((it + 1) & 1) * PSTRIDE;
            u64* dst = wvb + (size_t)((it + 1) & 1) * PSTRIDE;
            const unsigned prod = (unsigned)(it + 1);
            float w[4];
            poll4(src, tid, prod, w);
            float p[ROWS];
#pragma unroll
            for (int r = 0; r < ROWS; ++r) {
                float s = 0.0f;
#pragma unroll
                for (int q = 0; q < 4; ++q) s = fmaf(fR[r][q], w[q], s);
                p[r] = s;
            }
            float t = w[0] + w[1] + w[2] + w[3];
#pragma unroll
            for (int r = 0; r < ROWS; ++r) {
                float s = p[r];
#pragma unroll
                for (int m = 1; m < 64; m <<= 1) s += __shfl_xor(s, m, 64);
                if (lane == 0) red[1][wid][r] = s;
            }
#pragma unroll
            for (int m = 1; m < 64; m <<= 1) t += __shfl_xor(t, m, 64);
            if (lane == 0) red[1][wid][16] = t;
            __syncthreads();
            float tsum = 0.0f;
#pragma unroll
            for (int k = 0; k < 8; ++k) tsum += red[1][k][16];
            const float Tbin = ea * (tsum + eub);
            vb = vb + EPS_F * ((logbin - logf(Tbin)) / TAU_F - vb);
            if (tid < ROWS) {
                float T = ea * eub;
#pragma unroll
                for (int k = 0; k < 8; ++k) T += red[1][k][tid];
                const float vnew = (norm - logf(T)) / TAU_F;
                v = v + EPS_F * (vnew - v);
                __hip_atomic_store(dst + base + tid, make_pair(expf(v), prod),
                                   __ATOMIC_RELAXED, __HIP_MEMORY_SCOPE_AGENT);
            }
            evb = expf(vb);
        }
    }
    // publish final dustbin scalings once (tag 100 -> parity 0) for the epilogue
    if (lastb && tid == 0) {
        __hip_atomic_store(wub + NINNER, make_pair(eub, (unsigned)ITERS_N),
                           __ATOMIC_RELAXED, __HIP_MEMORY_SCOPE_AGENT);
        __hip_atomic_store(wvb + NINNER, make_pair(evb, (unsigned)ITERS_N),
                           __ATOMIC_RELAXED, __HIP_MEMORY_SCOPE_AGENT);
    }
}

// ---------------- K4: fused epilogue — out0 = exp(Z), row argmax, col argmax ----------
// final wu/wv: tag 100 (even) -> parity-0 buffer halves -> .x of float2 pairs
__global__ __launch_bounds__(256) void k_finish(const float* __restrict__ E,
                                                const float* __restrict__ F,
                                                const float2* __restrict__ wup,
                                                const float2* __restrict__ wvp,
                                                float* __restrict__ out,
                                                float* __restrict__ max0,
                                                int* __restrict__ idx0,
                                                int* __restrict__ idx1) {
    const int i = blockIdx.x;                 // 0..2048
    const int tid = threadIdx.x;
    const int lane = tid & 63, wid = tid >> 6;
    __shared__ float sb[4]; __shared__ int si[4];

    // --- row part: write out row i, argmax over inner cols ---
    {
        const float wui = wup[i].x * 4096.0f;     // * exp(-norm)
        const float* row = E + (size_t)i * SP;
        float best = -1.0f; int bidx = 0;
        for (int j = tid; j < NROW; j += 256) {
            const float val = row[j] * wvp[j].x * wui;
            out[(size_t)i * NROW + j] = val;
            if (j < NINNER && val > best) { best = val; bidx = j; }
        }
        if (i < NINNER) {
#pragma unroll
            for (int m = 1; m < 64; m <<= 1) {
                const float ob = __shfl_xor(best, m, 64);
                const int   oi = __shfl_xor(bidx, m, 64);
                if (ob > best || (ob == best && oi < bidx)) { best = ob; bidx = oi; }
            }
            if (lane == 0) { sb[wid] = best; si[wid] = bidx; }
            __syncthreads();
            if (tid == 0) {
                for (int k = 1; k < 4; ++k)
                    if (sb[k] > best || (sb[k] == best && si[k] < bidx)) { best = sb[k]; bidx = si[k]; }
                max0[i] = best; idx0[i] = bidx;
            }
        }
    }

    // --- col part: argmax of column i over inner rows (via F) ---
    if (i < NINNER) {
        __syncthreads();                          // sb/si reuse safety
        const float* row = F + (size_t)i * SP;
        float best = -1.0f; int bidx = 0;
        for (int r = tid; r < NINNER; r += 256) {
            const float q = row[r] * wup[r].x;
            if (q > best) { best = q; bidx = r; }
        }
#pragma unroll
        for (int m = 1; m < 64; m <<= 1) {
            const float ob = __shfl_xor(best, m, 64);
            const int   oi = __shfl_xor(bidx, m, 64);
            if (ob > best || (ob == best && oi < bidx)) { best = ob; bidx = oi; }
        }
        if (lane == 0) { sb[wid] = best; si[wid] = bidx; }
        __syncthreads();
        if (tid == 0) {
            for (int k = 1; k < 4; ++k)
                if (sb[k] > best || (sb[k] == best && si[k] < bidx)) { best = sb[k]; bidx = si[k]; }
            idx1[i] = bidx;
        }
    }
}

// ---------------- K5a/K5b: mutual matching ----------------
__global__ __launch_bounds__(256) void k_match0(const float* __restrict__ max0,
                                                const int* __restrict__ idx0,
                                                const int* __restrict__ idx1,
                                                float* __restrict__ ms0,
                                                int* __restrict__ vld0,
                                                float* __restrict__ out) {
    const int i = blockIdx.x * 256 + threadIdx.x;
    if (i >= NINNER) return;
    const int j = idx0[i];
    const bool mut = (idx1[j] == i);
    const float ms = mut ? max0[i] : 0.0f;
    const bool val = mut && (ms > 0.2f);
    ms0[i] = ms; vld0[i] = val ? 1 : 0;
    out[OOFF_I0 + i] = val ? (float)j : -1.0f;
    out[OOFF_S0 + i] = ms;
}
__global__ __launch_bounds__(256) void k_match1(const int* __restrict__ idx0,
                                                const int* __restrict__ idx1,
                                                const float* __restrict__ ms0,
                                                const int* __restrict__ vld0,
                                                float* __restrict__ out) {
    const int j = blockIdx.x * 256 + threadIdx.x;
    if (j >= NINNER) return;
    const int i = idx1[j];
    const bool mut = (idx0[i] == j);
    const float ms = mut ? ms0[i] : 0.0f;
    const bool val = mut && (vld0[i] != 0);
    out[OOFF_I1 + j] = val ? (float)i : -1.0f;
    out[OOFF_S1 + j] = ms;
}

// ---------------- host ----------------
extern "C" void kernel_launch(void* const* d_in, const int* in_sizes, int n_in,
                              void* d_out, int out_size, void* d_ws, size_t ws_size,
                              hipStream_t stream) {
    const float* A     = (const float*)d_in[0];   // mdesc0 (1,256,2048)
    const float* Bm    = (const float*)d_in[1];   // mdesc1 (1,256,2048)
    const float* alpha = (const float*)d_in[2];   // bin_score scalar

    float* ws = (float*)d_ws;
    float* E    = ws + OFF_E;
    float* F    = ws + OFF_F;
    u64*   wub  = (u64*)(ws + OFF_WUP);
    u64*   wvb  = (u64*)(ws + OFF_WVP);
    float* max0 = ws + OFF_MAX0;
    int*   idx0 = (int*)(ws + OFF_IDX0);
    int*   idx1 = (int*)(ws + OFF_IDX1);
    float* ms0  = ws + OFF_MS0;
    int*   vld0 = (int*)(ws + OFF_VLD0);
    float* out  = (float*)d_out;

    k_gemm<<<dim3(32, 32), 256, 0, stream>>>(A, Bm, E, F);
    k_init<<<dim3(16), 256, 0, stream>>>(E, F, wvb, alpha);
    k_sinkhorn<<<dim3(NB_S), NT_S, 0, stream>>>(E, F, wub, wvb, alpha);
    k_finish<<<dim3(NROW), 256, 0, stream>>>(E, F, (const float2*)wub, (const float2*)wvb,
                                             out, max0, idx0, idx1);
    k_match0<<<dim3(8), 256, 0, stream>>>(max0, idx0, idx1, ms0, vld0, out);
    k_match1<<<dim3(8), 256, 0, stream>>>(idx0, idx1, ms0, vld0, out);
}

// Round 3
// 1133.058 us; speedup vs baseline: 1.0982x; 1.0062x over previous
//
#include <hip/hip_runtime.h>
#include <math.h>

// ---------------- problem constants ----------------
#define D        256
#define NINNER   2048
#define NROW     2049          // 2048 + dustbin
#define SP       2064          // padded row stride (floats), 16B-aligned rows
#define ITERS_N  100
#define EPS_F    0.8f
#define TAU_F    1.02f
#define NB_S     128           // persistent sinkhorn blocks
#define NT_S     512           // threads per sinkhorn block
#define ROWS     16            // rows (cols) owned per block
#define QS       4             // polled slots per thread (2048 / NT_S)

typedef unsigned long long u64;

// pair buffers: u64 slots, (tag<<32)|float_bits, double-buffered by tag parity
#define PSTRIDE  2112u         // pairs per buffer (2048 iter slots + slot 2048 final-only)

// ws layout (in floats)
#define SZ_MAT   (2049u * 2064u)          // 4229136
#define OFF_E    0u
#define OFF_F    SZ_MAT
#define OFF_WUP  (2u * SZ_MAT)                  // u64[2][PSTRIDE] = 4*PSTRIDE floats
#define OFF_WVP  (OFF_WUP + 4u * PSTRIDE)
#define OFF_MAX0 (OFF_WVP + 4u * PSTRIDE)
#define OFF_IDX0 (OFF_MAX0 + 2048u)
#define OFF_IDX1 (OFF_IDX0 + 2048u)
#define OFF_MS0  (OFF_IDX1 + 2048u)
#define OFF_VLD0 (OFF_MS0 + 2048u)

// d_out layout (floats)
#define OOFF_I0  (2049u * 2049u)          // 4198401
#define OOFF_I1  (OOFF_I0 + 2048u)
#define OOFF_S0  (OOFF_I1 + 2048u)
#define OOFF_S1  (OOFF_S0 + 2048u)

__device__ __forceinline__ float    pair_val(u64 x) { return __uint_as_float((unsigned)x); }
__device__ __forceinline__ unsigned pair_tag(u64 x) { return (unsigned)(x >> 32); }
__device__ __forceinline__ u64 make_pair(float v, unsigned t) {
    return ((u64)t << 32) | (u64)__float_as_uint(v);
}

// ---------------- K1: fp32 GEMM -> E = exp(scores), F = E^T (fused) ----------------
__global__ __launch_bounds__(256) void k_gemm(const float* __restrict__ A,
                                              const float* __restrict__ Bm,
                                              float* __restrict__ E,
                                              float* __restrict__ F) {
    __shared__ float As[8][64];
    __shared__ float Bs[8][64];
    const int tid = threadIdx.x;
    const int tx = tid & 15, ty = tid >> 4;
    const int row0 = blockIdx.y * 64, col0 = blockIdx.x * 64;
    float acc[4][4] = {};
    const int lr = tid >> 6, lc = tid & 63;
    for (int k0 = 0; k0 < D; k0 += 8) {
        As[lr][lc]     = A[(k0 + lr) * NINNER + row0 + lc];
        As[lr + 4][lc] = A[(k0 + lr + 4) * NINNER + row0 + lc];
        Bs[lr][lc]     = Bm[(k0 + lr) * NINNER + col0 + lc];
        Bs[lr + 4][lc] = Bm[(k0 + lr + 4) * NINNER + col0 + lc];
        __syncthreads();
#pragma unroll
        for (int kk = 0; kk < 8; ++kk) {
            const float4 av = *(const float4*)&As[kk][ty * 4];
            const float4 bv = *(const float4*)&Bs[kk][tx * 4];
            const float a_[4] = {av.x, av.y, av.z, av.w};
            const float b_[4] = {bv.x, bv.y, bv.z, bv.w};
#pragma unroll
            for (int r = 0; r < 4; ++r)
#pragma unroll
                for (int c = 0; c < 4; ++c)
                    acc[r][c] = fmaf(a_[r], b_[c], acc[r][c]);
        }
        __syncthreads();
    }
    float o[4][4];
#pragma unroll
    for (int r = 0; r < 4; ++r)
#pragma unroll
        for (int c = 0; c < 4; ++c)
            o[r][c] = expf(acc[r][c] * 0.0625f);
    const int row = row0 + ty * 4, col = col0 + tx * 4;
#pragma unroll
    for (int r = 0; r < 4; ++r)     // E tile
        *(float4*)(E + (size_t)(row + r) * SP + col)
            = make_float4(o[r][0], o[r][1], o[r][2], o[r][3]);
#pragma unroll
    for (int c = 0; c < 4; ++c)     // F tile (transposed)
        *(float4*)(F + (size_t)(col + c) * SP + row)
            = make_float4(o[0][c], o[1][c], o[2][c], o[3][c]);
}

// ---------------- K2: bins for E and F + wv pair init (tag 0) ----------------
__global__ __launch_bounds__(256) void k_init(float* __restrict__ E,
                                              float* __restrict__ F,
                                              u64* __restrict__ wvb0,
                                              const float* __restrict__ alpha) {
    const int t = blockIdx.x * 256 + threadIdx.x;
    const float ea = expf(alpha[0]);
    if (t < NINNER) {
        E[(size_t)t * SP + NINNER] = ea;        // E bin column (for epilogue only)
        F[(size_t)t * SP + NINNER] = ea;        // F bin column
        wvb0[t] = make_pair(1.0f, 0u);          // v0 = 0 -> wv = 1, tag 0
    }
    if (t <= NINNER) {
        E[(size_t)NINNER * SP + t] = ea;        // E bin row (+corner)
        F[(size_t)NINNER * SP + t] = ea;        // F bin row (+corner)
    }
}

// ---------------- masked hot poll + light backoff (v0-proven protocol) ----------
// Fused tag+value 8B atoms: detection IS delivery (one L3 round trip after the
// producer's store lands). Masked re-poll: after the first round only missing
// slots are re-read, so straggler traffic is tiny.
__device__ __forceinline__ void poll4(const u64* buf, int tid, unsigned want, float* w) {
    u64 a[QS];
#pragma unroll
    for (int q = 0; q < QS; ++q)
        a[q] = __hip_atomic_load(buf + q * NT_S + tid, __ATOMIC_RELAXED, __HIP_MEMORY_SCOPE_AGENT);
    for (;;) {
        unsigned miss = 0u;
#pragma unroll
        for (int q = 0; q < QS; ++q)
            miss |= (pair_tag(a[q]) != want) ? (1u << q) : 0u;
        if (!miss) break;
        __builtin_amdgcn_s_sleep(2);     // ~128 cyc backoff: cut poll-storm contention
#pragma unroll
        for (int q = 0; q < QS; ++q)
            if (miss & (1u << q))
                a[q] = __hip_atomic_load(buf + q * NT_S + tid, __ATOMIC_RELAXED, __HIP_MEMORY_SCOPE_AGENT);
    }
#pragma unroll
    for (int q = 0; q < QS; ++q) w[q] = pair_val(a[q]);
}

// ---------------- K3: persistent Sinkhorn — barrier-free tagged dataflow ----------
// 128 blocks x 512 threads. Block b owns rows [16b,16b+16) of E and cols of F
// in registers (eR/fR[16][4]: thread t covers j in {q*512+t}). Same tagged
// parity-double-buffer protocol as the proven v0 kernel (skew bound < 2 iters
// per parity buffer; poisoned tags never match wanted tags 0..100). Halving
// consumer blocks halves the all-to-all fabric traffic per phase (the v0
// bottleneck); per-thread compute and register load are unchanged vs v0.
// Dustbin potentials locally replicated (bit-identical in every block).
__global__ __launch_bounds__(512, 2) void k_sinkhorn(const float* __restrict__ E,
                                                     const float* __restrict__ F,
                                                     u64* wub, u64* wvb,
                                                     const float* __restrict__ alpha) {
    const int b = blockIdx.x, tid = threadIdx.x;
    const int lane = tid & 63, wid = tid >> 6;
    const int base = b * ROWS;
    const bool lastb = (b == NB_S - 1);
    __shared__ float red[2][8][17];

    const float norm = -8.317766166719343f;            // -log(4096)
    const float logbin = 7.624618986159398f + norm;     // log(2048) + norm
    const float ea = expf(alpha[0]);

    float eR[ROWS][QS], fR[ROWS][QS];
#pragma unroll
    for (int r = 0; r < ROWS; ++r) {
        const float* rowE = E + (size_t)(base + r) * SP;
        const float* rowF = F + (size_t)(base + r) * SP;
#pragma unroll
        for (int q = 0; q < QS; ++q) {
            eR[r][q] = rowE[q * NT_S + tid];
            fR[r][q] = rowF[q * NT_S + tid];
        }
    }

    float u = 0.0f, v = 0.0f;              // potentials for row/col base+tid (tid<16)
    float ub = 0.0f, vb = 0.0f;            // dustbin potentials — local replicas
    float eub = 1.0f, evb = 1.0f;          // exp(ub), exp(vb)

    for (int it = 0; it < ITERS_N; ++it) {
        // ---- phase A: consume wv tag it, produce wu tag it+1 ----
        {
            const u64* src = wvb + (size_t)(it & 1) * PSTRIDE;
            u64* dst = wub + (size_t)((it + 1) & 1) * PSTRIDE;
            const unsigned prod = (unsigned)(it + 1);
            float w[QS];
            poll4(src, tid, (unsigned)it, w);
            float p[ROWS];
#pragma unroll
            for (int r = 0; r < ROWS; ++r) {
                float s = 0.0f;
#pragma unroll
                for (int q = 0; q < QS; ++q) s = fmaf(eR[r][q], w[q], s);
                p[r] = s;
            }
            float t = w[0] + w[1] + w[2] + w[3];
#pragma unroll
            for (int r = 0; r < ROWS; ++r) {
                float s = p[r];
#pragma unroll
                for (int m = 1; m < 64; m <<= 1) s += __shfl_xor(s, m, 64);
                if (lane == 0) red[0][wid][r] = s;
            }
#pragma unroll
            for (int m = 1; m < 64; m <<= 1) t += __shfl_xor(t, m, 64);
            if (lane == 0) red[0][wid][16] = t;
            __syncthreads();
            // local dustbin update (every thread, identical result)
            float tsum = 0.0f;
#pragma unroll
            for (int k = 0; k < 8; ++k) tsum += red[0][k][16];
            const float Sbin = ea * (tsum + evb);
            ub = ub + EPS_F * ((logbin - logf(Sbin)) / TAU_F - ub);
            if (tid < ROWS) {
                float S = ea * evb;
#pragma unroll
                for (int k = 0; k < 8; ++k) S += red[0][k][tid];
                const float unew = (norm - logf(S)) / TAU_F;
                u = u + EPS_F * (unew - u);
                __hip_atomic_store(dst + base + tid, make_pair(expf(u), prod),
                                   __ATOMIC_RELAXED, __HIP_MEMORY_SCOPE_AGENT);
            }
            eub = expf(ub);
        }
        // ---- phase B: consume wu tag it+1, produce wv tag it+1 ----
        {
            const u64* src = wub + (size_t)((it + 1) & 1) * PSTRIDE;
            u64* dst = wvb + (size_t)((it + 1) & 1) * PSTRIDE;
            const unsigned prod = (unsigned)(it + 1);
            float w[QS];
            poll4(src, tid, prod, w);
            float p[ROWS];
#pragma unroll
            for (int r = 0; r < ROWS; ++r) {
                float s = 0.0f;
#pragma unroll
                for (int q = 0; q < QS; ++q) s = fmaf(fR[r][q], w[q], s);
                p[r] = s;
            }
            float t = w[0] + w[1] + w[2] + w[3];
#pragma unroll
            for (int r = 0; r < ROWS; ++r) {
                float s = p[r];
#pragma unroll
                for (int m = 1; m < 64; m <<= 1) s += __shfl_xor(s, m, 64);
                if (lane == 0) red[1][wid][r] = s;
            }
#pragma unroll
            for (int m = 1; m < 64; m <<= 1) t += __shfl_xor(t, m, 64);
            if (lane == 0) red[1][wid][16] = t;
            __syncthreads();
            float tsum = 0.0f;
#pragma unroll
            for (int k = 0; k < 8; ++k) tsum += red[1][k][16];
            const float Tbin = ea * (tsum + eub);
            vb = vb + EPS_F * ((logbin - logf(Tbin)) / TAU_F - vb);
            if (tid < ROWS) {
                float T = ea * eub;
#pragma unroll
                for (int k = 0; k < 8; ++k) T += red[1][k][tid];
                const float vnew = (norm - logf(T)) / TAU_F;
                v = v + EPS_F * (vnew - v);
                __hip_atomic_store(dst + base + tid, make_pair(expf(v), prod),
                                   __ATOMIC_RELAXED, __HIP_MEMORY_SCOPE_AGENT);
            }
            evb = expf(vb);
        }
    }
    // publish final dustbin scalings once (tag 100 -> parity 0) for the epilogue
    if (lastb && tid == 0) {
        __hip_atomic_store(wub + NINNER, make_pair(eub, (unsigned)ITERS_N),
                           __ATOMIC_RELAXED, __HIP_MEMORY_SCOPE_AGENT);
        __hip_atomic_store(wvb + NINNER, make_pair(evb, (unsigned)ITERS_N),
                           __ATOMIC_RELAXED, __HIP_MEMORY_SCOPE_AGENT);
    }
}

// ---------------- K4: fused epilogue — out0 = exp(Z), row argmax, col argmax ----------
// final wu/wv: tag 100 (even) -> parity-0 buffer halves -> .x of float2 pairs
__global__ __launch_bounds__(256) void k_finish(const float* __restrict__ E,
                                                const float* __restrict__ F,
                                                const float2* __restrict__ wup,
                                                const float2* __restrict__ wvp,
                                                float* __restrict__ out,
                                                float* __restrict__ max0,
                                                int* __restrict__ idx0,
                                                int* __restrict__ idx1) {
    const int i = blockIdx.x;                 // 0..2048
    const int tid = threadIdx.x;
    const int lane = tid & 63, wid = tid >> 6;
    __shared__ float sb[4]; __shared__ int si[4];

    // --- row part: write out row i, argmax over inner cols ---
    {
        const float wui = wup[i].x * 4096.0f;     // * exp(-norm)
        const float* row = E + (size_t)i * SP;
        float best = -1.0f; int bidx = 0;
        for (int j = tid; j < NROW; j += 256) {
            const float val = row[j] * wvp[j].x * wui;
            out[(size_t)i * NROW + j] = val;
            if (j < NINNER && val > best) { best = val; bidx = j; }
        }
        if (i < NINNER) {
#pragma unroll
            for (int m = 1; m < 64; m <<= 1) {
                const float ob = __shfl_xor(best, m, 64);
                const int   oi = __shfl_xor(bidx, m, 64);
                if (ob > best || (ob == best && oi < bidx)) { best = ob; bidx = oi; }
            }
            if (lane == 0) { sb[wid] = best; si[wid] = bidx; }
            __syncthreads();
            if (tid == 0) {
                for (int k = 1; k < 4; ++k)
                    if (sb[k] > best || (sb[k] == best && si[k] < bidx)) { best = sb[k]; bidx = si[k]; }
                max0[i] = best; idx0[i] = bidx;
            }
        }
    }

    // --- col part: argmax of column i over inner rows (via F) ---
    if (i < NINNER) {
        __syncthreads();                          // sb/si reuse safety
        const float* row = F + (size_t)i * SP;
        float best = -1.0f; int bidx = 0;
        for (int r = tid; r < NINNER; r += 256) {
            const float q = row[r] * wup[r].x;
            if (q > best) { best = q; bidx = r; }
        }
#pragma unroll
        for (int m = 1; m < 64; m <<= 1) {
            const float ob = __shfl_xor(best, m, 64);
            const int   oi = __shfl_xor(bidx, m, 64);
            if (ob > best || (ob == best && oi < bidx)) { best = ob; bidx = oi; }
        }
        if (lane == 0) { sb[wid] = best; si[wid] = bidx; }
        __syncthreads();
        if (tid == 0) {
            for (int k = 1; k < 4; ++k)
                if (sb[k] > best || (sb[k] == best && si[k] < bidx)) { best = sb[k]; bidx = si[k]; }
            idx1[i] = bidx;
        }
    }
}

// ---------------- K5a/K5b: mutual matching ----------------
__global__ __launch_bounds__(256) void k_match0(const float* __restrict__ max0,
                                                const int* __restrict__ idx0,
                                                const int* __restrict__ idx1,
                                                float* __restrict__ ms0,
                                                int* __restrict__ vld0,
                                                float* __restrict__ out) {
    const int i = blockIdx.x * 256 + threadIdx.x;
    if (i >= NINNER) return;
    const int j = idx0[i];
    const bool mut = (idx1[j] == i);
    const float ms = mut ? max0[i] : 0.0f;
    const bool val = mut && (ms > 0.2f);
    ms0[i] = ms; vld0[i] = val ? 1 : 0;
    out[OOFF_I0 + i] = val ? (float)j : -1.0f;
    out[OOFF_S0 + i] = ms;
}
__global__ __launch_bounds__(256) void k_match1(const int* __restrict__ idx0,
                                                const int* __restrict__ idx1,
                                                const float* __restrict__ ms0,
                                                const int* __restrict__ vld0,
                                                float* __restrict__ out) {
    const int j = blockIdx.x * 256 + threadIdx.x;
    if (j >= NINNER) return;
    const int i = idx1[j];
    const bool mut = (idx0[i] == j);
    const float ms = mut ? ms0[i] : 0.0f;
    const bool val = mut && (vld0[i] != 0);
    out[OOFF_I1 + j] = val ? (float)i : -1.0f;
    out[OOFF_S1 + j] = ms;
}

// ---------------- host ----------------
extern "C" void kernel_launch(void* const* d_in, const int* in_sizes, int n_in,
                              void* d_out, int out_size, void* d_ws, size_t ws_size,
                              hipStream_t stream) {
    const float* A     = (const float*)d_in[0];   // mdesc0 (1,256,2048)
    const float* Bm    = (const float*)d_in[1];   // mdesc1 (1,256,2048)
    const float* alpha = (const float*)d_in[2];   // bin_score scalar

    float* ws = (float*)d_ws;
    float* E    = ws + OFF_E;
    float* F    = ws + OFF_F;
    u64*   wub  = (u64*)(ws + OFF_WUP);
    u64*   wvb  = (u64*)(ws + OFF_WVP);
    float* max0 = ws + OFF_MAX0;
    int*   idx0 = (int*)(ws + OFF_IDX0);
    int*   idx1 = (int*)(ws + OFF_IDX1);
    float* ms0  = ws + OFF_MS0;
    int*   vld0 = (int*)(ws + OFF_VLD0);
    float* out  = (float*)d_out;

    k_gemm<<<dim3(32, 32), 256, 0, stream>>>(A, Bm, E, F);
    k_init<<<dim3(16), 256, 0, stream>>>(E, F, wvb, alpha);
    k_sinkhorn<<<dim3(NB_S), NT_S, 0, stream>>>(E, F, wub, wvb, alpha);
    k_finish<<<dim3(NROW), 256, 0, stream>>>(E, F, (const float2*)wub, (const float2*)wvb,
                                             out, max0, idx0, idx1);
    k_match0<<<dim3(8), 256, 0, stream>>>(max0, idx0, idx1, ms0, vld0, out);
    k_match1<<<dim3(8), 256, 0, stream>>>(idx0, idx1, ms0, vld0, out);
}

// Round 4
// 919.416 us; speedup vs baseline: 1.3534x; 1.2324x over previous
//
#include <hip/hip_runtime.h>
#include <math.h>

// ---------------- problem constants ----------------
#define D        256
#define NINNER   2048
#define NROW     2049          // 2048 + dustbin
#define SP       2064          // padded row stride (floats), 16B-aligned rows
#define ITERS_N  100
#define EPS_F    0.8f
#define TAU_F    1.02f
#define NB       256           // persistent blocks
#define NT       256           // threads per block

typedef unsigned long long u64;

// pair buffers: u64 slots, (tag<<32)|float_bits, double-buffered by tag parity
#define PSTRIDE  2112u         // pairs per buffer (2048 iter slots + slot 2048 final-only)

// ws layout (in floats)
#define SZ_MAT   (2049u * 2064u)          // 4229136
#define OFF_E    0u
#define OFF_F    SZ_MAT
#define OFF_WUP  (2u * SZ_MAT)                  // u64[2][PSTRIDE] = 4*PSTRIDE floats
#define OFF_WVP  (OFF_WUP + 4u * PSTRIDE)
#define OFF_MAX0 (OFF_WVP + 4u * PSTRIDE)
#define OFF_IDX0 (OFF_MAX0 + 2048u)
#define OFF_IDX1 (OFF_IDX0 + 2048u)

// d_out layout (floats)
#define OOFF_I0  (2049u * 2049u)          // 4198401
#define OOFF_I1  (OOFF_I0 + 2048u)
#define OOFF_S0  (OOFF_I1 + 2048u)
#define OOFF_S1  (OOFF_S0 + 2048u)

__device__ __forceinline__ float    pair_val(u64 x) { return __uint_as_float((unsigned)x); }
__device__ __forceinline__ unsigned pair_tag(u64 x) { return (unsigned)(x >> 32); }
__device__ __forceinline__ u64 make_pair(float v, unsigned t) {
    return ((u64)t << 32) | (u64)__float_as_uint(v);
}

// ---------------- K1: fp32 GEMM -> E = exp(scores), F = E^T (fused) ----------------
// 128x128 tile per block, 8x8 accumulator per thread (16x16 thread grid).
// 256 blocks = 1/CU; 4x fewer barriers per FLOP than the old 64x64 version.
__global__ __launch_bounds__(256) void k_gemm(const float* __restrict__ A,
                                              const float* __restrict__ Bm,
                                              float* __restrict__ E,
                                              float* __restrict__ F) {
    __shared__ float As[8][128];
    __shared__ float Bs[8][128];
    const int tid = threadIdx.x;
    const int tx = tid & 15, ty = tid >> 4;          // 16x16 threads
    const int row0 = blockIdx.y * 128, col0 = blockIdx.x * 128;
    float acc[8][8] = {};
    const int lr = tid >> 5;              // 0..7 : k-row in staging tile
    const int lc = (tid & 31) * 4;        // 0..124 : col, float4 each
    for (int k0 = 0; k0 < D; k0 += 8) {
        *(float4*)&As[lr][lc] = *(const float4*)&A[(size_t)(k0 + lr) * NINNER + row0 + lc];
        *(float4*)&Bs[lr][lc] = *(const float4*)&Bm[(size_t)(k0 + lr) * NINNER + col0 + lc];
        __syncthreads();
#pragma unroll
        for (int kk = 0; kk < 8; ++kk) {
            float a_[8], b_[8];
            *(float4*)&a_[0] = *(const float4*)&As[kk][ty * 8];
            *(float4*)&a_[4] = *(const float4*)&As[kk][ty * 8 + 4];
            *(float4*)&b_[0] = *(const float4*)&Bs[kk][tx * 8];
            *(float4*)&b_[4] = *(const float4*)&Bs[kk][tx * 8 + 4];
#pragma unroll
            for (int r = 0; r < 8; ++r)
#pragma unroll
                for (int c = 0; c < 8; ++c)
                    acc[r][c] = fmaf(a_[r], b_[c], acc[r][c]);
        }
        __syncthreads();
    }
    float o[8][8];
#pragma unroll
    for (int r = 0; r < 8; ++r)
#pragma unroll
        for (int c = 0; c < 8; ++c)
            o[r][c] = expf(acc[r][c] * 0.0625f);
    const int row = row0 + ty * 8, col = col0 + tx * 8;
#pragma unroll
    for (int r = 0; r < 8; ++r) {   // E tile
        *(float4*)(E + (size_t)(row + r) * SP + col)
            = make_float4(o[r][0], o[r][1], o[r][2], o[r][3]);
        *(float4*)(E + (size_t)(row + r) * SP + col + 4)
            = make_float4(o[r][4], o[r][5], o[r][6], o[r][7]);
    }
#pragma unroll
    for (int c = 0; c < 8; ++c) {   // F tile (transposed)
        *(float4*)(F + (size_t)(col + c) * SP + row)
            = make_float4(o[0][c], o[1][c], o[2][c], o[3][c]);
        *(float4*)(F + (size_t)(col + c) * SP + row + 4)
            = make_float4(o[4][c], o[5][c], o[6][c], o[7][c]);
    }
}

// ---------------- K2: bins for E and F + wv pair init (tag 0) ----------------
__global__ __launch_bounds__(256) void k_init(float* __restrict__ E,
                                              float* __restrict__ F,
                                              u64* __restrict__ wvb0,
                                              const float* __restrict__ alpha) {
    const int t = blockIdx.x * 256 + threadIdx.x;
    const float ea = expf(alpha[0]);
    if (t < NINNER) {
        E[(size_t)t * SP + NINNER] = ea;        // E bin column (for epilogue only)
        F[(size_t)t * SP + NINNER] = ea;        // F bin column
        wvb0[t] = make_pair(1.0f, 0u);          // v0 = 0 -> wv = 1, tag 0
    }
    if (t <= NINNER) {
        E[(size_t)NINNER * SP + t] = ea;        // E bin row (+corner)
        F[(size_t)NINNER * SP + t] = ea;        // F bin row (+corner)
    }
}

// ---------------- masked hot poll + light backoff ----------------
__device__ __forceinline__ void poll8(const u64* buf, int tid, unsigned want, float* w) {
    u64 a[8];
#pragma unroll
    for (int q = 0; q < 8; ++q)
        a[q] = __hip_atomic_load(buf + q * 256 + tid, __ATOMIC_RELAXED, __HIP_MEMORY_SCOPE_AGENT);
    for (;;) {
        unsigned miss = 0u;
#pragma unroll
        for (int q = 0; q < 8; ++q)
            miss |= (pair_tag(a[q]) != want) ? (1u << q) : 0u;
        if (!miss) break;
        __builtin_amdgcn_s_sleep(2);     // ~128 cyc backoff: cut poll-storm contention
#pragma unroll
        for (int q = 0; q < 8; ++q)
            if (miss & (1u << q))
                a[q] = __hip_atomic_load(buf + q * 256 + tid, __ATOMIC_RELAXED, __HIP_MEMORY_SCOPE_AGENT);
    }
#pragma unroll
    for (int q = 0; q < 8; ++q) w[q] = pair_val(a[q]);
}

// ---------------- K3: persistent Sinkhorn — barrier-free tagged dataflow ----------------
// (verbatim restore of the proven 800µs kernel — 256 blocks x 256 threads)
// Block b owns rows [8b,8b+8) of E and cols [8b,8b+8) of F in registers.
// wu/wv (inner 2048 only) exchanged as (tag,value) 8B atoms, double-buffered
// by tag parity. Dustbin potentials locally replicated. Skew bound < 2 iters
// per parity buffer => no deadlock; poison never matches wanted tags 0..100.
__global__ __launch_bounds__(256, 1) void k_sinkhorn(const float* __restrict__ E,
                                                     const float* __restrict__ F,
                                                     u64* wub, u64* wvb,
                                                     const float* __restrict__ alpha) {
    const int b = blockIdx.x, tid = threadIdx.x;
    const int lane = tid & 63, wid = tid >> 6;
    const int base = b * 8;
    const bool lastb = (b == NB - 1);
    __shared__ float red[2][4][9];

    const float norm = -8.317766166719343f;            // -log(4096)
    const float logbin = 7.624618986159398f + norm;     // log(2048) + norm
    const float ea = expf(alpha[0]);

    float eR[8][8], fR[8][8];
#pragma unroll
    for (int r = 0; r < 8; ++r) {
        const float* rowE = E + (size_t)(base + r) * SP;
        const float* rowF = F + (size_t)(base + r) * SP;
#pragma unroll
        for (int q = 0; q < 8; ++q) {
            eR[r][q] = rowE[q * 256 + tid];
            fR[r][q] = rowF[q * 256 + tid];
        }
    }

    float u = 0.0f, v = 0.0f;              // potentials for row/col base+tid (tid<8)
    float ub = 0.0f, vb = 0.0f;            // dustbin potentials — local replicas
    float eub = 1.0f, evb = 1.0f;          // exp(ub), exp(vb)

    for (int it = 0; it < ITERS_N; ++it) {
        // ---- phase A: consume wv tag it, produce wu tag it+1 ----
        {
            const u64* src = wvb + (size_t)(it & 1) * PSTRIDE;
            u64* dst = wub + (size_t)((it + 1) & 1) * PSTRIDE;
            const unsigned prod = (unsigned)(it + 1);
            float w[8];
            poll8(src, tid, (unsigned)it, w);
            float p[8];
#pragma unroll
            for (int r = 0; r < 8; ++r) {
                float s = 0.0f;
#pragma unroll
                for (int q = 0; q < 8; ++q) s = fmaf(eR[r][q], w[q], s);
                p[r] = s;
            }
            float t = w[0] + w[1] + w[2] + w[3] + w[4] + w[5] + w[6] + w[7];
#pragma unroll
            for (int r = 0; r < 8; ++r) {
                float s = p[r];
#pragma unroll
                for (int m = 1; m < 64; m <<= 1) s += __shfl_xor(s, m, 64);
                if (lane == 0) red[0][wid][r] = s;
            }
#pragma unroll
            for (int m = 1; m < 64; m <<= 1) t += __shfl_xor(t, m, 64);
            if (lane == 0) red[0][wid][8] = t;
            __syncthreads();
            // local dustbin update (every thread, identical result)
            const float tsum = red[0][0][8] + red[0][1][8] + red[0][2][8] + red[0][3][8];
            const float Sbin = ea * (tsum + evb);
            ub = ub + EPS_F * ((logbin - logf(Sbin)) / TAU_F - ub);
            if (tid < 8) {
                const float S = red[0][0][tid] + red[0][1][tid] + red[0][2][tid] + red[0][3][tid]
                              + ea * evb;
                const float unew = (norm - logf(S)) / TAU_F;
                u = u + EPS_F * (unew - u);
                __hip_atomic_store(dst + base + tid, make_pair(expf(u), prod),
                                   __ATOMIC_RELAXED, __HIP_MEMORY_SCOPE_AGENT);
            }
            eub = expf(ub);
        }
        // ---- phase B: consume wu tag it+1, produce wv tag it+1 ----
        {
            const u64* src = wub + (size_t)((it + 1) & 1) * PSTRIDE;
            u64* dst = wvb + (size_t)((it + 1) & 1) * PSTRIDE;
            const unsigned prod = (unsigned)(it + 1);
            float w[8];
            poll8(src, tid, prod, w);
            float p[8];
#pragma unroll
            for (int r = 0; r < 8; ++r) {
                float s = 0.0f;
#pragma unroll
                for (int q = 0; q < 8; ++q) s = fmaf(fR[r][q], w[q], s);
                p[r] = s;
            }
            float t = w[0] + w[1] + w[2] + w[3] + w[4] + w[5] + w[6] + w[7];
#pragma unroll
            for (int r = 0; r < 8; ++r) {
                float s = p[r];
#pragma unroll
                for (int m = 1; m < 64; m <<= 1) s += __shfl_xor(s, m, 64);
                if (lane == 0) red[1][wid][r] = s;
            }
#pragma unroll
            for (int m = 1; m < 64; m <<= 1) t += __shfl_xor(t, m, 64);
            if (lane == 0) red[1][wid][8] = t;
            __syncthreads();
            const float tsum = red[1][0][8] + red[1][1][8] + red[1][2][8] + red[1][3][8];
            const float Tbin = ea * (tsum + eub);
            vb = vb + EPS_F * ((logbin - logf(Tbin)) / TAU_F - vb);
            if (tid < 8) {
                const float T = red[1][0][tid] + red[1][1][tid] + red[1][2][tid] + red[1][3][tid]
                              + ea * eub;
                const float vnew = (norm - logf(T)) / TAU_F;
                v = v + EPS_F * (vnew - v);
                __hip_atomic_store(dst + base + tid, make_pair(expf(v), prod),
                                   __ATOMIC_RELAXED, __HIP_MEMORY_SCOPE_AGENT);
            }
            evb = expf(vb);
        }
    }
    // publish final dustbin scalings once (tag 100 -> parity 0) for the epilogue
    if (lastb && tid == 0) {
        __hip_atomic_store(wub + NINNER, make_pair(eub, (unsigned)ITERS_N),
                           __ATOMIC_RELAXED, __HIP_MEMORY_SCOPE_AGENT);
        __hip_atomic_store(wvb + NINNER, make_pair(evb, (unsigned)ITERS_N),
                           __ATOMIC_RELAXED, __HIP_MEMORY_SCOPE_AGENT);
    }
}

// ---------------- K4: fused epilogue — out0 = exp(Z), row argmax, col argmax ----------
// final wu/wv: tag 100 (even) -> parity-0 buffer halves -> .x of float2 pairs
__global__ __launch_bounds__(256) void k_finish(const float* __restrict__ E,
                                                const float* __restrict__ F,
                                                const float2* __restrict__ wup,
                                                const float2* __restrict__ wvp,
                                                float* __restrict__ out,
                                                float* __restrict__ max0,
                                                int* __restrict__ idx0,
                                                int* __restrict__ idx1) {
    const int i = blockIdx.x;                 // 0..2048
    const int tid = threadIdx.x;
    const int lane = tid & 63, wid = tid >> 6;
    __shared__ float sb[4]; __shared__ int si[4];

    // --- row part: write out row i, argmax over inner cols ---
    {
        const float wui = wup[i].x * 4096.0f;     // * exp(-norm)
        const float* row = E + (size_t)i * SP;
        float best = -1.0f; int bidx = 0;
        for (int j = tid; j < NROW; j += 256) {
            const float val = row[j] * wvp[j].x * wui;
            out[(size_t)i * NROW + j] = val;
            if (j < NINNER && val > best) { best = val; bidx = j; }
        }
        if (i < NINNER) {
#pragma unroll
            for (int m = 1; m < 64; m <<= 1) {
                const float ob = __shfl_xor(best, m, 64);
                const int   oi = __shfl_xor(bidx, m, 64);
                if (ob > best || (ob == best && oi < bidx)) { best = ob; bidx = oi; }
            }
            if (lane == 0) { sb[wid] = best; si[wid] = bidx; }
            __syncthreads();
            if (tid == 0) {
                for (int k = 1; k < 4; ++k)
                    if (sb[k] > best || (sb[k] == best && si[k] < bidx)) { best = sb[k]; bidx = si[k]; }
                max0[i] = best; idx0[i] = bidx;
            }
        }
    }

    // --- col part: argmax of column i over inner rows (via F) ---
    if (i < NINNER) {
        __syncthreads();                          // sb/si reuse safety
        const float* row = F + (size_t)i * SP;
        float best = -1.0f; int bidx = 0;
        for (int r = tid; r < NINNER; r += 256) {
            const float q = row[r] * wup[r].x;
            if (q > best) { best = q; bidx = r; }
        }
#pragma unroll
        for (int m = 1; m < 64; m <<= 1) {
            const float ob = __shfl_xor(best, m, 64);
            const int   oi = __shfl_xor(bidx, m, 64);
            if (ob > best || (ob == best && oi < bidx)) { best = ob; bidx = oi; }
        }
        if (lane == 0) { sb[wid] = best; si[wid] = bidx; }
        __syncthreads();
        if (tid == 0) {
            for (int k = 1; k < 4; ++k)
                if (sb[k] > best || (sb[k] == best && si[k] < bidx)) { best = sb[k]; bidx = si[k]; }
            idx1[i] = bidx;
        }
    }
}

// ---------------- K5: fused mutual matching (single block, LDS-staged) ----------------
__global__ __launch_bounds__(256) void k_match(const float* __restrict__ max0,
                                               const int* __restrict__ idx0,
                                               const int* __restrict__ idx1,
                                               float* __restrict__ out) {
    const int tid = threadIdx.x;
    __shared__ float ms0s[NINNER];
    __shared__ int   vlds[NINNER];
    for (int i = tid; i < NINNER; i += 256) {
        const int j = idx0[i];
        const bool mut = (idx1[j] == i);
        const float ms = mut ? max0[i] : 0.0f;
        const bool val = mut && (ms > 0.2f);
        ms0s[i] = ms; vlds[i] = val ? 1 : 0;
        out[OOFF_I0 + i] = val ? (float)j : -1.0f;
        out[OOFF_S0 + i] = ms;
    }
    __syncthreads();
    for (int j = tid; j < NINNER; j += 256) {
        const int i = idx1[j];
        const bool mut = (idx0[i] == j);
        const float ms = mut ? ms0s[i] : 0.0f;
        const bool val = mut && (vlds[i] != 0);
        out[OOFF_I1 + j] = val ? (float)i : -1.0f;
        out[OOFF_S1 + j] = ms;
    }
}

// ---------------- host ----------------
extern "C" void kernel_launch(void* const* d_in, const int* in_sizes, int n_in,
                              void* d_out, int out_size, void* d_ws, size_t ws_size,
                              hipStream_t stream) {
    const float* A     = (const float*)d_in[0];   // mdesc0 (1,256,2048)
    const float* Bm    = (const float*)d_in[1];   // mdesc1 (1,256,2048)
    const float* alpha = (const float*)d_in[2];   // bin_score scalar

    float* ws = (float*)d_ws;
    float* E    = ws + OFF_E;
    float* F    = ws + OFF_F;
    u64*   wub  = (u64*)(ws + OFF_WUP);
    u64*   wvb  = (u64*)(ws + OFF_WVP);
    float* max0 = ws + OFF_MAX0;
    int*   idx0 = (int*)(ws + OFF_IDX0);
    int*   idx1 = (int*)(ws + OFF_IDX1);
    float* out  = (float*)d_out;

    k_gemm<<<dim3(16, 16), 256, 0, stream>>>(A, Bm, E, F);
    k_init<<<dim3(16), 256, 0, stream>>>(E, F, wvb, alpha);
    k_sinkhorn<<<dim3(NB), NT, 0, stream>>>(E, F, wub, wvb, alpha);
    k_finish<<<dim3(NROW), 256, 0, stream>>>(E, F, (const float2*)wub, (const float2*)wvb,
                                             out, max0, idx0, idx1);
    k_match<<<dim3(1), 256, 0, stream>>>(max0, idx0, idx1, out);
}

// Round 5
// 903.941 us; speedup vs baseline: 1.3766x; 1.0171x over previous
//
#include <hip/hip_runtime.h>
#include <math.h>

// ---------------- problem constants ----------------
#define D        256
#define NINNER   2048
#define NROW     2049          // 2048 + dustbin
#define SP       2064          // padded row stride (floats), 16B-aligned rows
#define ITERS_N  100
#define EPS_F    0.8f
#define TAU_F    1.02f
#define NB       256           // persistent blocks
#define NT       256           // threads per block

typedef unsigned long long u64;

// pair buffers: u64 slots, (tag<<32)|float_bits, double-buffered by tag parity
#define PSTRIDE  2112u         // pairs per buffer (2048 iter slots + slot 2048 final-only)

// ws layout (in floats)
#define SZ_MAT   (2049u * 2064u)          // 4229136
#define OFF_E    0u
#define OFF_F    SZ_MAT
#define OFF_WUP  (2u * SZ_MAT)                  // u64[2][PSTRIDE] = 4*PSTRIDE floats
#define OFF_WVP  (OFF_WUP + 4u * PSTRIDE)
#define OFF_MAX0 (OFF_WVP + 4u * PSTRIDE)
#define OFF_IDX0 (OFF_MAX0 + 2048u)
#define OFF_IDX1 (OFF_IDX0 + 2048u)

// d_out layout (floats)
#define OOFF_I0  (2049u * 2049u)          // 4198401
#define OOFF_I1  (OOFF_I0 + 2048u)
#define OOFF_S0  (OOFF_I1 + 2048u)
#define OOFF_S1  (OOFF_S0 + 2048u)

__device__ __forceinline__ float    pair_val(u64 x) { return __uint_as_float((unsigned)x); }
__device__ __forceinline__ unsigned pair_tag(u64 x) { return (unsigned)(x >> 32); }
__device__ __forceinline__ u64 make_pair(float v, unsigned t) {
    return ((u64)t << 32) | (u64)__float_as_uint(v);
}

// ---------------- K1: fp32 GEMM -> E = exp(scores), F = E^T (fused) ----------------
// Proven 64x64-tile version (1024 blocks, 4/CU — best latency hiding measured).
// Block (0,0) additionally folds in the old k_init work (bins + wv tag-0 init);
// kernel-boundary writeback guarantees visibility to k_sinkhorn's agent loads.
__global__ __launch_bounds__(256) void k_gemm(const float* __restrict__ A,
                                              const float* __restrict__ Bm,
                                              float* __restrict__ E,
                                              float* __restrict__ F,
                                              u64* __restrict__ wvb0,
                                              const float* __restrict__ alpha) {
    __shared__ float As[8][64];
    __shared__ float Bs[8][64];
    const int tid = threadIdx.x;
    const int tx = tid & 15, ty = tid >> 4;
    const int row0 = blockIdx.y * 64, col0 = blockIdx.x * 64;
    float acc[4][4] = {};
    const int lr = tid >> 6, lc = tid & 63;
    for (int k0 = 0; k0 < D; k0 += 8) {
        As[lr][lc]     = A[(k0 + lr) * NINNER + row0 + lc];
        As[lr + 4][lc] = A[(k0 + lr + 4) * NINNER + row0 + lc];
        Bs[lr][lc]     = Bm[(k0 + lr) * NINNER + col0 + lc];
        Bs[lr + 4][lc] = Bm[(k0 + lr + 4) * NINNER + col0 + lc];
        __syncthreads();
#pragma unroll
        for (int kk = 0; kk < 8; ++kk) {
            const float4 av = *(const float4*)&As[kk][ty * 4];
            const float4 bv = *(const float4*)&Bs[kk][tx * 4];
            const float a_[4] = {av.x, av.y, av.z, av.w};
            const float b_[4] = {bv.x, bv.y, bv.z, bv.w};
#pragma unroll
            for (int r = 0; r < 4; ++r)
#pragma unroll
                for (int c = 0; c < 4; ++c)
                    acc[r][c] = fmaf(a_[r], b_[c], acc[r][c]);
        }
        __syncthreads();
    }
    float o[4][4];
#pragma unroll
    for (int r = 0; r < 4; ++r)
#pragma unroll
        for (int c = 0; c < 4; ++c)
            o[r][c] = expf(acc[r][c] * 0.0625f);
    const int row = row0 + ty * 4, col = col0 + tx * 4;
#pragma unroll
    for (int r = 0; r < 4; ++r)     // E tile
        *(float4*)(E + (size_t)(row + r) * SP + col)
            = make_float4(o[r][0], o[r][1], o[r][2], o[r][3]);
#pragma unroll
    for (int c = 0; c < 4; ++c)     // F tile (transposed)
        *(float4*)(F + (size_t)(col + c) * SP + row)
            = make_float4(o[0][c], o[1][c], o[2][c], o[3][c]);

    // ---- folded k_init: bins for E/F + wv pair init (tag 0) ----
    if (blockIdx.x == 0 && blockIdx.y == 0) {
        const float ea = expf(alpha[0]);
        for (int t = tid; t < NINNER; t += 256) {
            E[(size_t)t * SP + NINNER] = ea;    // E bin column (epilogue only)
            F[(size_t)t * SP + NINNER] = ea;    // F bin column
            wvb0[t] = make_pair(1.0f, 0u);      // v0 = 0 -> wv = 1, tag 0
        }
        for (int t = tid; t <= NINNER; t += 256) {
            E[(size_t)NINNER * SP + t] = ea;    // E bin row (+corner)
            F[(size_t)NINNER * SP + t] = ea;    // F bin row (+corner)
        }
    }
}

// ---------------- masked hot poll + light backoff ----------------
__device__ __forceinline__ void poll8(const u64* buf, int tid, unsigned want, float* w) {
    u64 a[8];
#pragma unroll
    for (int q = 0; q < 8; ++q)
        a[q] = __hip_atomic_load(buf + q * 256 + tid, __ATOMIC_RELAXED, __HIP_MEMORY_SCOPE_AGENT);
    for (;;) {
        unsigned miss = 0u;
#pragma unroll
        for (int q = 0; q < 8; ++q)
            miss |= (pair_tag(a[q]) != want) ? (1u << q) : 0u;
        if (!miss) break;
        __builtin_amdgcn_s_sleep(2);     // ~128 cyc backoff: cut poll-storm contention
#pragma unroll
        for (int q = 0; q < 8; ++q)
            if (miss & (1u << q))
                a[q] = __hip_atomic_load(buf + q * 256 + tid, __ATOMIC_RELAXED, __HIP_MEMORY_SCOPE_AGENT);
    }
#pragma unroll
    for (int q = 0; q < 8; ++q) w[q] = pair_val(a[q]);
}

// ---------------- K3: persistent Sinkhorn — barrier-free tagged dataflow ----------------
// (verbatim: best-measured 793-796 µs configuration — DO NOT TOUCH)
// Block b owns rows [8b,8b+8) of E and cols [8b,8b+8) of F in registers.
// wu/wv (inner 2048 only) exchanged as (tag,value) 8B atoms, double-buffered
// by tag parity. Dustbin potentials locally replicated. Skew bound < 2 iters
// per parity buffer => no deadlock; poison never matches wanted tags 0..100.
__global__ __launch_bounds__(256, 1) void k_sinkhorn(const float* __restrict__ E,
                                                     const float* __restrict__ F,
                                                     u64* wub, u64* wvb,
                                                     const float* __restrict__ alpha) {
    const int b = blockIdx.x, tid = threadIdx.x;
    const int lane = tid & 63, wid = tid >> 6;
    const int base = b * 8;
    const bool lastb = (b == NB - 1);
    __shared__ float red[2][4][9];

    const float norm = -8.317766166719343f;            // -log(4096)
    const float logbin = 7.624618986159398f + norm;     // log(2048) + norm
    const float ea = expf(alpha[0]);

    float eR[8][8], fR[8][8];
#pragma unroll
    for (int r = 0; r < 8; ++r) {
        const float* rowE = E + (size_t)(base + r) * SP;
        const float* rowF = F + (size_t)(base + r) * SP;
#pragma unroll
        for (int q = 0; q < 8; ++q) {
            eR[r][q] = rowE[q * 256 + tid];
            fR[r][q] = rowF[q * 256 + tid];
        }
    }

    float u = 0.0f, v = 0.0f;              // potentials for row/col base+tid (tid<8)
    float ub = 0.0f, vb = 0.0f;            // dustbin potentials — local replicas
    float eub = 1.0f, evb = 1.0f;          // exp(ub), exp(vb)

    for (int it = 0; it < ITERS_N; ++it) {
        // ---- phase A: consume wv tag it, produce wu tag it+1 ----
        {
            const u64* src = wvb + (size_t)(it & 1) * PSTRIDE;
            u64* dst = wub + (size_t)((it + 1) & 1) * PSTRIDE;
            const unsigned prod = (unsigned)(it + 1);
            float w[8];
            poll8(src, tid, (unsigned)it, w);
            float p[8];
#pragma unroll
            for (int r = 0; r < 8; ++r) {
                float s = 0.0f;
#pragma unroll
                for (int q = 0; q < 8; ++q) s = fmaf(eR[r][q], w[q], s);
                p[r] = s;
            }
            float t = w[0] + w[1] + w[2] + w[3] + w[4] + w[5] + w[6] + w[7];
#pragma unroll
            for (int r = 0; r < 8; ++r) {
                float s = p[r];
#pragma unroll
                for (int m = 1; m < 64; m <<= 1) s += __shfl_xor(s, m, 64);
                if (lane == 0) red[0][wid][r] = s;
            }
#pragma unroll
            for (int m = 1; m < 64; m <<= 1) t += __shfl_xor(t, m, 64);
            if (lane == 0) red[0][wid][8] = t;
            __syncthreads();
            // local dustbin update (every thread, identical result)
            const float tsum = red[0][0][8] + red[0][1][8] + red[0][2][8] + red[0][3][8];
            const float Sbin = ea * (tsum + evb);
            ub = ub + EPS_F * ((logbin - logf(Sbin)) / TAU_F - ub);
            if (tid < 8) {
                const float S = red[0][0][tid] + red[0][1][tid] + red[0][2][tid] + red[0][3][tid]
                              + ea * evb;
                const float unew = (norm - logf(S)) / TAU_F;
                u = u + EPS_F * (unew - u);
                __hip_atomic_store(dst + base + tid, make_pair(expf(u), prod),
                                   __ATOMIC_RELAXED, __HIP_MEMORY_SCOPE_AGENT);
            }
            eub = expf(ub);
        }
        // ---- phase B: consume wu tag it+1, produce wv tag it+1 ----
        {
            const u64* src = wub + (size_t)((it + 1) & 1) * PSTRIDE;
            u64* dst = wvb + (size_t)((it + 1) & 1) * PSTRIDE;
            const unsigned prod = (unsigned)(it + 1);
            float w[8];
            poll8(src, tid, prod, w);
            float p[8];
#pragma unroll
            for (int r = 0; r < 8; ++r) {
                float s = 0.0f;
#pragma unroll
                for (int q = 0; q < 8; ++q) s = fmaf(fR[r][q], w[q], s);
                p[r] = s;
            }
            float t = w[0] + w[1] + w[2] + w[3] + w[4] + w[5] + w[6] + w[7];
#pragma unroll
            for (int r = 0; r < 8; ++r) {
                float s = p[r];
#pragma unroll
                for (int m = 1; m < 64; m <<= 1) s += __shfl_xor(s, m, 64);
                if (lane == 0) red[1][wid][r] = s;
            }
#pragma unroll
            for (int m = 1; m < 64; m <<= 1) t += __shfl_xor(t, m, 64);
            if (lane == 0) red[1][wid][8] = t;
            __syncthreads();
            const float tsum = red[1][0][8] + red[1][1][8] + red[1][2][8] + red[1][3][8];
            const float Tbin = ea * (tsum + eub);
            vb = vb + EPS_F * ((logbin - logf(Tbin)) / TAU_F - vb);
            if (tid < 8) {
                const float T = red[1][0][tid] + red[1][1][tid] + red[1][2][tid] + red[1][3][tid]
                              + ea * eub;
                const float vnew = (norm - logf(T)) / TAU_F;
                v = v + EPS_F * (vnew - v);
                __hip_atomic_store(dst + base + tid, make_pair(expf(v), prod),
                                   __ATOMIC_RELAXED, __HIP_MEMORY_SCOPE_AGENT);
            }
            evb = expf(vb);
        }
    }
    // publish final dustbin scalings once (tag 100 -> parity 0) for the epilogue
    if (lastb && tid == 0) {
        __hip_atomic_store(wub + NINNER, make_pair(eub, (unsigned)ITERS_N),
                           __ATOMIC_RELAXED, __HIP_MEMORY_SCOPE_AGENT);
        __hip_atomic_store(wvb + NINNER, make_pair(evb, (unsigned)ITERS_N),
                           __ATOMIC_RELAXED, __HIP_MEMORY_SCOPE_AGENT);
    }
}

// ---------------- K4: fused epilogue — out0 = exp(Z), row argmax, col argmax ----------
// final wu/wv: tag 100 (even) -> parity-0 buffer halves -> .x of float2 pairs
__global__ __launch_bounds__(256) void k_finish(const float* __restrict__ E,
                                                const float* __restrict__ F,
                                                const float2* __restrict__ wup,
                                                const float2* __restrict__ wvp,
                                                float* __restrict__ out,
                                                float* __restrict__ max0,
                                                int* __restrict__ idx0,
                                                int* __restrict__ idx1) {
    const int i = blockIdx.x;                 // 0..2048
    const int tid = threadIdx.x;
    const int lane = tid & 63, wid = tid >> 6;
    __shared__ float sb[4]; __shared__ int si[4];

    // --- row part: write out row i, argmax over inner cols ---
    {
        const float wui = wup[i].x * 4096.0f;     // * exp(-norm)
        const float* row = E + (size_t)i * SP;
        float best = -1.0f; int bidx = 0;
        for (int j = tid; j < NROW; j += 256) {
            const float val = row[j] * wvp[j].x * wui;
            out[(size_t)i * NROW + j] = val;
            if (j < NINNER && val > best) { best = val; bidx = j; }
        }
        if (i < NINNER) {
#pragma unroll
            for (int m = 1; m < 64; m <<= 1) {
                const float ob = __shfl_xor(best, m, 64);
                const int   oi = __shfl_xor(bidx, m, 64);
                if (ob > best || (ob == best && oi < bidx)) { best = ob; bidx = oi; }
            }
            if (lane == 0) { sb[wid] = best; si[wid] = bidx; }
            __syncthreads();
            if (tid == 0) {
                for (int k = 1; k < 4; ++k)
                    if (sb[k] > best || (sb[k] == best && si[k] < bidx)) { best = sb[k]; bidx = si[k]; }
                max0[i] = best; idx0[i] = bidx;
            }
        }
    }

    // --- col part: argmax of column i over inner rows (via F) ---
    if (i < NINNER) {
        __syncthreads();                          // sb/si reuse safety
        const float* row = F + (size_t)i * SP;
        float best = -1.0f; int bidx = 0;
        for (int r = tid; r < NINNER; r += 256) {
            const float q = row[r] * wup[r].x;
            if (q > best) { best = q; bidx = r; }
        }
#pragma unroll
        for (int m = 1; m < 64; m <<= 1) {
            const float ob = __shfl_xor(best, m, 64);
            const int   oi = __shfl_xor(bidx, m, 64);
            if (ob > best || (ob == best && oi < bidx)) { best = ob; bidx = oi; }
        }
        if (lane == 0) { sb[wid] = best; si[wid] = bidx; }
        __syncthreads();
        if (tid == 0) {
            for (int k = 1; k < 4; ++k)
                if (sb[k] > best || (sb[k] == best && si[k] < bidx)) { best = sb[k]; bidx = si[k]; }
            idx1[i] = bidx;
        }
    }
}

// ---------------- K5: fused mutual matching (single block, LDS-staged) ----------------
__global__ __launch_bounds__(256) void k_match(const float* __restrict__ max0,
                                               const int* __restrict__ idx0,
                                               const int* __restrict__ idx1,
                                               float* __restrict__ out) {
    const int tid = threadIdx.x;
    __shared__ float ms0s[NINNER];
    __shared__ int   vlds[NINNER];
    for (int i = tid; i < NINNER; i += 256) {
        const int j = idx0[i];
        const bool mut = (idx1[j] == i);
        const float ms = mut ? max0[i] : 0.0f;
        const bool val = mut && (ms > 0.2f);
        ms0s[i] = ms; vlds[i] = val ? 1 : 0;
        out[OOFF_I0 + i] = val ? (float)j : -1.0f;
        out[OOFF_S0 + i] = ms;
    }
    __syncthreads();
    for (int j = tid; j < NINNER; j += 256) {
        const int i = idx1[j];
        const bool mut = (idx0[i] == j);
        const float ms = mut ? ms0s[i] : 0.0f;
        const bool val = mut && (vlds[i] != 0);
        out[OOFF_I1 + j] = val ? (float)i : -1.0f;
        out[OOFF_S1 + j] = ms;
    }
}

// ---------------- host ----------------
extern "C" void kernel_launch(void* const* d_in, const int* in_sizes, int n_in,
                              void* d_out, int out_size, void* d_ws, size_t ws_size,
                              hipStream_t stream) {
    const float* A     = (const float*)d_in[0];   // mdesc0 (1,256,2048)
    const float* Bm    = (const float*)d_in[1];   // mdesc1 (1,256,2048)
    const float* alpha = (const float*)d_in[2];   // bin_score scalar

    float* ws = (float*)d_ws;
    float* E    = ws + OFF_E;
    float* F    = ws + OFF_F;
    u64*   wub  = (u64*)(ws + OFF_WUP);
    u64*   wvb  = (u64*)(ws + OFF_WVP);
    float* max0 = ws + OFF_MAX0;
    int*   idx0 = (int*)(ws + OFF_IDX0);
    int*   idx1 = (int*)(ws + OFF_IDX1);
    float* out  = (float*)d_out;

    k_gemm<<<dim3(32, 32), 256, 0, stream>>>(A, Bm, E, F, wvb, alpha);
    k_sinkhorn<<<dim3(NB), NT, 0, stream>>>(E, F, wub, wvb, alpha);
    k_finish<<<dim3(NROW), 256, 0, stream>>>(E, F, (const float2*)wub, (const float2*)wvb,
                                             out, max0, idx0, idx1);
    k_match<<<dim3(1), 256, 0, stream>>>(max0, idx0, idx1, out);
}